// Round 11
// baseline (516.122 us; speedup 1.0000x reference)
//
#include <hip/hip_runtime.h>
#include <hip/hip_bf16.h>
#include <stdint.h>

#define K_DIM 4096
#define N_DIM 11008
#define GROUP 128

typedef __attribute__((ext_vector_type(8))) __bf16 bf16x8;
typedef __attribute__((ext_vector_type(4))) float f32x4;
typedef __attribute__((address_space(3))) uint8_t lds_u8;
typedef __attribute__((address_space(3))) void lds_void;
typedef __attribute__((address_space(1))) const void g_void;

static __device__ inline __bf16 f2bf(float f) { return (__bf16)f; }

// ================= prepass 1: x fp32 -> bf16 ([M][K] row-major) =================
__global__ __launch_bounds__(256) void cvt_x_kernel(const float* __restrict__ x,
                                                    __bf16* __restrict__ xb, int total8) {
    int t = blockIdx.x * 256 + threadIdx.x;
    if (t >= total8) return;
    f32x4 a0 = *(const f32x4*)(x + (size_t)t * 8);
    f32x4 a1 = *(const f32x4*)(x + (size_t)t * 8 + 4);
    bf16x8 v;
    #pragma unroll
    for (int j = 0; j < 4; ++j) { v[j] = f2bf(a0[j]); v[j + 4] = f2bf(a1[j]); }
    *(bf16x8*)(xb + (size_t)t * 8) = v;
}

// ============ prepass 2: dequant W int4 -> bf16, stored TRANSPOSED [N][K] ============
__global__ __launch_bounds__(256) void dequant_w_kernel(const int* __restrict__ qw,
                                                        const int* __restrict__ qz,
                                                        const float* __restrict__ sc,
                                                        __bf16* __restrict__ wb) {
    const int n   = blockIdx.x * 256 + threadIdx.x;
    const int kb0 = blockIdx.y * 8;
    const int g   = blockIdx.y >> 1;
    const float s   = sc[(size_t)g * N_DIM + n];
    const float nzs = -(float)((qz[(size_t)g * (N_DIM / 8) + (n >> 3)] >> ((n & 7) * 4)) & 15) * s;
    #pragma unroll
    for (int j = 0; j < 8; ++j) {
        const int w = qw[(size_t)(kb0 + j) * N_DIM + n];
        bf16x8 v;
        #pragma unroll
        for (int b = 0; b < 8; ++b)
            v[b] = f2bf(fmaf((float)((w >> (4 * b)) & 15), s, nzs));
        *(bf16x8*)(wb + (size_t)n * K_DIM + (size_t)(kb0 + j) * 8) = v;
    }
}

// ================= main GEMM: 128x128 tile, BK=64, 4 waves, 2 blocks/CU =================
// r3/r9-proven sync skeleton (2 barriers/K-tile, counted vmcnt(8), 16x16x32 MFMA,
// chunk-XOR swizzle) at HALF the tile so LDS = 64KB -> 2 INDEPENDENT blocks per CU.
// Rationale (r10 post-mortem): at 1 block/CU every barrier idles the whole CU; a
// co-resident independent block fills the sync stalls (m114 co-scheduling).
// Wave tile 64x64 (4 waves 2x2): 16 reads + 32 MFMA per K-tile per wave.
#define BM2 128
#define BN2 128
#define BK2 64
#define NT  (K_DIM / BK2)   // 64

__global__ __launch_bounds__(256, 2) void gemm128_kernel(
    const __bf16* __restrict__ xb, const __bf16* __restrict__ wb,
    const float* __restrict__ bias, float* __restrict__ out)
{
    __shared__ __align__(16) __bf16 As[2][BM2 * BK2];   // 2 x 16 KiB
    __shared__ __align__(16) __bf16 Bs[2][BN2 * BK2];   // 2 x 16 KiB

    const int tid  = threadIdx.x;
    const int lane = tid & 63;
    const int wid  = tid >> 6;             // 4 waves: 2(M) x 2(N)
    const int wm = (wid >> 1) * 64;
    const int wn = (wid & 1) * 64;

    // XCD-bijective swizzle: grid 2752 = 8 * 344
    const int bid = blockIdx.x;
    const int wg  = (bid & 7) * 344 + (bid >> 3);
    const int m0 = (wg / 86) * BM2;
    const int n0 = (wg % 86) * BN2;

    // staging: A/B each 128 rows x 8 chunks = 1024 chunks; 4 per thread per operand.
    // stored position p=ch&7 holds global chunk p ^ (row&7) (involution per row).
    const __bf16* pa[4];
    const __bf16* pb[4];
    int chk[4];
    #pragma unroll
    for (int l = 0; l < 4; ++l) {
        const int ch  = l * 256 + tid;         // 0..1023
        const int row = ch >> 3;
        const int g   = (ch & 7) ^ (row & 7);
        chk[l] = ch;
        pa[l] = xb + (size_t)(m0 + row) * K_DIM + g * 8;
        pb[l] = wb + (size_t)(n0 + row) * K_DIM + g * 8;
    }
    lds_u8* baseA = (lds_u8*)&As[0][0];
    lds_u8* baseB = (lds_u8*)&Bs[0][0];

    auto STAGE = [&](int buf, int kofs) {   // 4 A + 4 B loads per thread
        lds_u8* dA_ = baseA + buf * (BM2 * BK2 * 2);
        lds_u8* dB_ = baseB + buf * (BN2 * BK2 * 2);
        #pragma unroll
        for (int l = 0; l < 4; ++l)
            __builtin_amdgcn_global_load_lds((g_void*)(pa[l] + kofs),
                                             (lds_void*)(dA_ + chk[l] * 16), 16, 0, 0);
        #pragma unroll
        for (int l = 0; l < 4; ++l)
            __builtin_amdgcn_global_load_lds((g_void*)(pb[l] + kofs),
                                             (lds_void*)(dB_ + chk[l] * 16), 16, 0, 0);
    };

    // fragment read addressing (swizzle folded in; frag rows differ from fr by x16)
    const int fr  = lane & 15;
    const int fc  = lane >> 4;
    const int swz = fr & 7;
    const int col0 = (fc ^ swz) * 8;           // kk = 0
    const int col1 = ((4 + fc) ^ swz) * 8;     // kk = 1
    const int rowoffA = (wm + fr) * BK2;       // elems
    const int rowoffB = (wn + fr) * BK2;

    f32x4 acc[4][4];
    #pragma unroll
    for (int m = 0; m < 4; ++m)
        #pragma unroll
        for (int n = 0; n < 4; ++n) acc[m][n] = (f32x4){0.f, 0.f, 0.f, 0.f};

    // ---- prologue: tiles 0 and 1 in flight, wait for tile 0 ----
    STAGE(0, 0);
    STAGE(1, BK2);
    asm volatile("s_waitcnt vmcnt(8)" ::: "memory");
    __builtin_amdgcn_sched_barrier(0);
    __builtin_amdgcn_s_barrier();
    __builtin_amdgcn_sched_barrier(0);

    for (int t = 0; t < NT; ++t) {
        const int cur = t & 1;
        const __bf16* ra = &As[0][0] + cur * (BM2 * BK2) + rowoffA;
        const __bf16* rb = &Bs[0][0] + cur * (BN2 * BK2) + rowoffB;
        bf16x8 aR[4], bR[8], a2[4];

        // ---- phase A: read bR(all 8) + aR(m0-1); MFMA (m0-1 x n0-3) ----
        #pragma unroll
        for (int n = 0; n < 4; ++n) {
            bR[n * 2 + 0] = *(const bf16x8*)(rb + n * 1024 + col0);
            bR[n * 2 + 1] = *(const bf16x8*)(rb + n * 1024 + col1);
        }
        #pragma unroll
        for (int m = 0; m < 2; ++m) {
            aR[m * 2 + 0] = *(const bf16x8*)(ra + m * 1024 + col0);
            aR[m * 2 + 1] = *(const bf16x8*)(ra + m * 1024 + col1);
        }
        __builtin_amdgcn_s_setprio(1);
        #pragma unroll
        for (int m = 0; m < 2; ++m)
            #pragma unroll
            for (int n = 0; n < 4; ++n)
                #pragma unroll
                for (int kk = 0; kk < 2; ++kk)
                    acc[m][n] = __builtin_amdgcn_mfma_f32_16x16x32_bf16(
                        aR[m * 2 + kk], bR[n * 2 + kk], acc[m][n], 0, 0, 0);
        __builtin_amdgcn_s_setprio(0);

        // ---- phase C: read a2(m2-3); fence; barrier; prefetch t+2; MFMA rest ----
        #pragma unroll
        for (int m = 0; m < 2; ++m) {
            a2[m * 2 + 0] = *(const bf16x8*)(ra + (m + 2) * 1024 + col0);
            a2[m * 2 + 1] = *(const bf16x8*)(ra + (m + 2) * 1024 + col1);
        }
        asm volatile("s_waitcnt lgkmcnt(0)" ::: "memory");   // my reads of buf[cur] done
        __builtin_amdgcn_sched_barrier(0);
        __builtin_amdgcn_s_barrier();                        // all waves done reading buf[cur]
        __builtin_amdgcn_sched_barrier(0);
        if (t + 2 < NT) STAGE(cur, (t + 2) * BK2);           // overwrite buf[cur] with tile t+2

        __builtin_amdgcn_s_setprio(1);
        #pragma unroll
        for (int m = 0; m < 2; ++m)
            #pragma unroll
            for (int n = 0; n < 4; ++n)
                #pragma unroll
                for (int kk = 0; kk < 2; ++kk)
                    acc[m + 2][n] = __builtin_amdgcn_mfma_f32_16x16x32_bf16(
                        a2[m * 2 + kk], bR[n * 2 + kk], acc[m + 2][n], 0, 0, 0);
        __builtin_amdgcn_s_setprio(0);

        // tile t+1 (8 oldest outstanding loads) must be complete before next iter
        if (t + 2 < NT) { asm volatile("s_waitcnt vmcnt(8)" ::: "memory"); }
        else            { asm volatile("s_waitcnt vmcnt(0)" ::: "memory"); }
        __builtin_amdgcn_sched_barrier(0);
        __builtin_amdgcn_s_barrier();
        __builtin_amdgcn_sched_barrier(0);
    }

    // ---- epilogue: C/D layout col=lane&15, row=(lane>>4)*4+r ----
    const int cn  = lane & 15;
    const int cr4 = (lane >> 4) * 4;
    #pragma unroll
    for (int n = 0; n < 4; ++n) {
        const int col = n0 + wn + n * 16 + cn;
        const float bv = bias[col];
        #pragma unroll
        for (int m = 0; m < 4; ++m) {
            const int row = m0 + wm + m * 16 + cr4;
            #pragma unroll
            for (int r = 0; r < 4; ++r)
                out[(size_t)(row + r) * N_DIM + col] = acc[m][n][r] + bv;
        }
    }
}

// ================= fallback: fused kernel (if ws too small) =================
#define FBM 128
#define FBN 128
#define FBK 32
#define FLDSS 40
__global__ __launch_bounds__(256) void gptq_gemm_fused_kernel(
    const float* __restrict__ x, const int* __restrict__ qw, const int* __restrict__ qz,
    const float* __restrict__ sc, const float* __restrict__ bias, float* __restrict__ out)
{
    __shared__ __align__(16) __bf16 Asm[FBM][FLDSS];
    __shared__ __align__(16) __bf16 Bsm[FBN][FLDSS];
    const int tid = threadIdx.x, lane = tid & 63, wid = tid >> 6;
    const int m0 = blockIdx.y * FBM, n0 = blockIdx.x * FBN;
    const int wm = (wid >> 1) * 64, wn = (wid & 1) * 64;
    f32x4 acc[4][4];
    #pragma unroll
    for (int i = 0; i < 4; ++i)
        #pragma unroll
        for (int j = 0; j < 4; ++j) acc[i][j] = (f32x4){0.f, 0.f, 0.f, 0.f};
    const int a_m = tid >> 2, a_h = tid & 3;
    const int b_n = tid & 127, b_k8 = tid >> 7;
    const int ng = n0 + b_n, zsh = (ng & 7) * 4;
    const int fr = lane & 15, fc = lane >> 4;
    for (int k0 = 0; k0 < K_DIM; k0 += FBK) {
        const int g = k0 >> 7;
        const float* xa = x + (size_t)(m0 + a_m) * K_DIM + k0 + a_h * 8;
        f32x4 a0 = *(const f32x4*)xa;
        f32x4 a1 = *(const f32x4*)(xa + 4);
        const float* xbp = xa + (size_t)64 * K_DIM;
        f32x4 a2 = *(const f32x4*)xbp;
        f32x4 a3 = *(const f32x4*)(xbp + 4);
        const int kb = (k0 >> 3) + b_k8;
        const int w0 = qw[(size_t)kb * N_DIM + ng];
        const int w1 = qw[(size_t)(kb + 2) * N_DIM + ng];
        const float s = sc[(size_t)g * N_DIM + ng];
        const float nzs = -(float)((qz[(size_t)g * (N_DIM / 8) + (ng >> 3)] >> zsh) & 15) * s;
        __syncthreads();
        bf16x8 av0, av1;
        #pragma unroll
        for (int j = 0; j < 4; ++j) {
            av0[j] = f2bf(a0[j]); av0[j + 4] = f2bf(a1[j]);
            av1[j] = f2bf(a2[j]); av1[j + 4] = f2bf(a3[j]);
        }
        *(bf16x8*)&Asm[a_m][a_h * 8] = av0;
        *(bf16x8*)&Asm[a_m + 64][a_h * 8] = av1;
        bf16x8 bv0, bv1;
        #pragma unroll
        for (int j = 0; j < 8; ++j) {
            bv0[j] = f2bf(fmaf((float)((w0 >> (4 * j)) & 15), s, nzs));
            bv1[j] = f2bf(fmaf((float)((w1 >> (4 * j)) & 15), s, nzs));
        }
        *(bf16x8*)&Bsm[b_n][b_k8 * 8] = bv0;
        *(bf16x8*)&Bsm[b_n][(b_k8 + 2) * 8] = bv1;
        __syncthreads();
        bf16x8 af[4], bfr[4];
        #pragma unroll
        for (int i = 0; i < 4; ++i) af[i] = *(const bf16x8*)&Asm[wm + i * 16 + fr][fc * 8];
        #pragma unroll
        for (int j = 0; j < 4; ++j) bfr[j] = *(const bf16x8*)&Bsm[wn + j * 16 + fr][fc * 8];
        #pragma unroll
        for (int i = 0; i < 4; ++i)
            #pragma unroll
            for (int j = 0; j < 4; ++j)
                acc[i][j] = __builtin_amdgcn_mfma_f32_16x16x32_bf16(af[i], bfr[j], acc[i][j], 0, 0, 0);
    }
    const int cn = lane & 15, cr4 = (lane >> 4) * 4;
    #pragma unroll
    for (int j = 0; j < 4; ++j) {
        const int col = n0 + wn + j * 16 + cn;
        const float bv = bias[col];
        #pragma unroll
        for (int i = 0; i < 4; ++i) {
            const int row = m0 + wm + i * 16 + cr4;
            #pragma unroll
            for (int r = 0; r < 4; ++r)
                out[(size_t)(row + r) * N_DIM + col] = acc[i][j][r] + bv;
        }
    }
}

extern "C" void kernel_launch(void* const* d_in, const int* in_sizes, int n_in,
                              void* d_out, int out_size, void* d_ws, size_t ws_size,
                              hipStream_t stream) {
    const float* x    = (const float*)d_in[0];
    const int*   qw   = (const int*)d_in[1];
    const int*   qz   = (const int*)d_in[2];
    const float* sc   = (const float*)d_in[3];
    const float* bias = (const float*)d_in[4];
    float* out = (float*)d_out;
    const int M = in_sizes[0] / K_DIM;   // 4096

    const size_t xb_bytes = (size_t)M * K_DIM * sizeof(__bf16);        // 32 MiB
    const size_t wb_bytes = (size_t)N_DIM * K_DIM * sizeof(__bf16);    // 86 MiB
    if (ws_size >= xb_bytes + wb_bytes && (M % BM2) == 0) {
        __bf16* xb = (__bf16*)d_ws;
        __bf16* wb = (__bf16*)((uint8_t*)d_ws + xb_bytes);
        const int total8 = M * K_DIM / 8;
        cvt_x_kernel<<<dim3(total8 / 256), dim3(256), 0, stream>>>(x, xb, total8);
        dequant_w_kernel<<<dim3(N_DIM / 256, K_DIM / 8 / 8), dim3(256), 0, stream>>>(qw, qz, sc, wb);
        const int nblocks = (N_DIM / BN2) * (M / BM2);   // 86 * 32 = 2752
        gemm128_kernel<<<dim3(nblocks), dim3(256), 0, stream>>>(xb, wb, bias, out);
    } else {
        gptq_gemm_fused_kernel<<<dim3(N_DIM / FBN, M / FBM), dim3(256), 0, stream>>>(x, qw, qz, sc, bias, out);
    }
}

// Round 12
// 417.341 us; speedup vs baseline: 1.2367x; 1.2367x over previous
//
#include <hip/hip_runtime.h>
#include <hip/hip_bf16.h>
#include <stdint.h>

#define K_DIM 4096
#define N_DIM 11008
#define GROUP 128

typedef __attribute__((ext_vector_type(8))) __bf16 bf16x8;
typedef __attribute__((ext_vector_type(4))) float f32x4;
typedef __attribute__((address_space(3))) uint8_t lds_u8;
typedef __attribute__((address_space(3))) void lds_void;
typedef __attribute__((address_space(1))) const void g_void;

static __device__ inline __bf16 f2bf(float f) { return (__bf16)f; }

// ================= prepass 1: x fp32 -> bf16 ([M][K] row-major) =================
__global__ __launch_bounds__(256) void cvt_x_kernel(const float* __restrict__ x,
                                                    __bf16* __restrict__ xb, int total8) {
    int t = blockIdx.x * 256 + threadIdx.x;
    if (t >= total8) return;
    f32x4 a0 = *(const f32x4*)(x + (size_t)t * 8);
    f32x4 a1 = *(const f32x4*)(x + (size_t)t * 8 + 4);
    bf16x8 v;
    #pragma unroll
    for (int j = 0; j < 4; ++j) { v[j] = f2bf(a0[j]); v[j + 4] = f2bf(a1[j]); }
    *(bf16x8*)(xb + (size_t)t * 8) = v;
}

// ============ prepass 2: dequant W int4 -> bf16, stored TRANSPOSED [N][K] ============
__global__ __launch_bounds__(256) void dequant_w_kernel(const int* __restrict__ qw,
                                                        const int* __restrict__ qz,
                                                        const float* __restrict__ sc,
                                                        __bf16* __restrict__ wb) {
    const int n   = blockIdx.x * 256 + threadIdx.x;
    const int kb0 = blockIdx.y * 8;
    const int g   = blockIdx.y >> 1;
    const float s   = sc[(size_t)g * N_DIM + n];
    const float nzs = -(float)((qz[(size_t)g * (N_DIM / 8) + (n >> 3)] >> ((n & 7) * 4)) & 15) * s;
    #pragma unroll
    for (int j = 0; j < 8; ++j) {
        const int w = qw[(size_t)(kb0 + j) * N_DIM + n];
        bf16x8 v;
        #pragma unroll
        for (int b = 0; b < 8; ++b)
            v[b] = f2bf(fmaf((float)((w >> (4 * b)) & 15), s, nzs));
        *(bf16x8*)(wb + (size_t)n * K_DIM + (size_t)(kb0 + j) * 8) = v;
    }
}

// ================= main GEMM: 256x256 tile, BK=64, 8 waves =================
// EXACT r3/r9 skeleton (session best anchor: GEMM 382us). ONE change: kk is now the
// OUTERMOST loop in every MFMA block, so consecutive MFMAs hit distinct accumulators
// (independent). Previously kk was innermost -> 32 back-to-back dependent MFMA pairs
// per wave-tile, each paying dep-latency the 2-wave/SIMD scheduler can't fully hide.
#define BM2 256
#define BN2 256
#define BK2 64
#define NT  (K_DIM / BK2)   // 64

__global__ __launch_bounds__(512, 2) void gemm256_kernel(
    const __bf16* __restrict__ xb, const __bf16* __restrict__ wb,
    const float* __restrict__ bias, float* __restrict__ out)
{
    __shared__ __align__(16) __bf16 As[2][BM2 * BK2];   // 2 x 32 KiB
    __shared__ __align__(16) __bf16 Bs[2][BN2 * BK2];   // 2 x 32 KiB

    const int tid  = threadIdx.x;
    const int lane = tid & 63;
    const int wid  = tid >> 6;             // 8 waves: 2(M) x 4(N)
    const int wm = (wid >> 2) * 128;
    const int wn = (wid & 3) * 64;

    // XCD-bijective swizzle: grid 688 = 8 * 86
    const int bid = blockIdx.x;
    const int wg  = (bid & 7) * 86 + (bid >> 3);
    const int m0 = (wg / 43) * BM2;
    const int n0 = (wg % 43) * BN2;

    // ---- staging: 4 x 16B chunks per thread per operand per K-tile ----
    const __bf16* pa[4];
    const __bf16* pb[4];
    int chk[4];
    #pragma unroll
    for (int l = 0; l < 4; ++l) {
        const int ch  = l * 512 + tid;         // 0..2047
        const int row = ch >> 3;
        const int g   = (ch & 7) ^ (row & 7);  // involution per row
        chk[l] = ch;
        pa[l] = xb + (size_t)(m0 + row) * K_DIM + g * 8;
        pb[l] = wb + (size_t)(n0 + row) * K_DIM + g * 8;
    }
    lds_u8* baseA = (lds_u8*)&As[0][0];
    lds_u8* baseB = (lds_u8*)&Bs[0][0];

    auto STAGE = [&](int buf, int kofs) {
        lds_u8* dA_ = baseA + buf * (BM2 * BK2 * 2);
        lds_u8* dB_ = baseB + buf * (BN2 * BK2 * 2);
        #pragma unroll
        for (int l = 0; l < 4; ++l)
            __builtin_amdgcn_global_load_lds((g_void*)(pa[l] + kofs),
                                             (lds_void*)(dA_ + chk[l] * 16), 16, 0, 0);
        #pragma unroll
        for (int l = 0; l < 4; ++l)
            __builtin_amdgcn_global_load_lds((g_void*)(pb[l] + kofs),
                                             (lds_void*)(dB_ + chk[l] * 16), 16, 0, 0);
    };

    // ---- fragment read addressing (swizzle folded in) ----
    const int fr  = lane & 15;
    const int fc  = lane >> 4;
    const int swz = fr & 7;
    const int col0 = (fc ^ swz) * 8;           // kk = 0
    const int col1 = ((4 + fc) ^ swz) * 8;     // kk = 1
    const int rowoffA = (wm + fr) * BK2;       // elems
    const int rowoffB = (wn + fr) * BK2;

    f32x4 acc[8][4];
    #pragma unroll
    for (int m = 0; m < 8; ++m)
        #pragma unroll
        for (int n = 0; n < 4; ++n) acc[m][n] = (f32x4){0.f, 0.f, 0.f, 0.f};

    // ---- prologue: tiles 0 and 1 in flight, wait for tile 0 ----
    STAGE(0, 0);
    STAGE(1, BK2);
    asm volatile("s_waitcnt vmcnt(8)" ::: "memory");
    __builtin_amdgcn_sched_barrier(0);
    __builtin_amdgcn_s_barrier();
    __builtin_amdgcn_sched_barrier(0);

    for (int t = 0; t < NT; ++t) {
        const int cur = t & 1;
        const __bf16* ra = &As[0][0] + cur * (BM2 * BK2) + rowoffA;
        const __bf16* rb = &Bs[0][0] + cur * (BN2 * BK2) + rowoffB;
        bf16x8 aR[8], bR[8], a2[8];

        // ---- phase A: b(n=0,1) + a(m=0..3) reads, MFMA quadrant (mh0,nh0) ----
        #pragma unroll
        for (int n = 0; n < 2; ++n) {
            bR[n * 2 + 0] = *(const bf16x8*)(rb + n * 1024 + col0);
            bR[n * 2 + 1] = *(const bf16x8*)(rb + n * 1024 + col1);
        }
        #pragma unroll
        for (int m = 0; m < 4; ++m) {
            aR[m * 2 + 0] = *(const bf16x8*)(ra + m * 1024 + col0);
            aR[m * 2 + 1] = *(const bf16x8*)(ra + m * 1024 + col1);
        }
        __builtin_amdgcn_s_setprio(1);
        #pragma unroll
        for (int kk = 0; kk < 2; ++kk)                       // kk OUTER: 8 indep MFMA per kk
            #pragma unroll
            for (int m = 0; m < 4; ++m)
                #pragma unroll
                for (int n = 0; n < 2; ++n)
                    acc[m][n] = __builtin_amdgcn_mfma_f32_16x16x32_bf16(
                        aR[m * 2 + kk], bR[n * 2 + kk], acc[m][n], 0, 0, 0);
        __builtin_amdgcn_s_setprio(0);

        // ---- phase B: b(n=2,3) reads, MFMA quadrant (mh0,nh1) ----
        #pragma unroll
        for (int n = 2; n < 4; ++n) {
            bR[n * 2 + 0] = *(const bf16x8*)(rb + n * 1024 + col0);
            bR[n * 2 + 1] = *(const bf16x8*)(rb + n * 1024 + col1);
        }
        __builtin_amdgcn_s_setprio(1);
        #pragma unroll
        for (int kk = 0; kk < 2; ++kk)                       // kk OUTER
            #pragma unroll
            for (int m = 0; m < 4; ++m)
                #pragma unroll
                for (int n = 2; n < 4; ++n)
                    acc[m][n] = __builtin_amdgcn_mfma_f32_16x16x32_bf16(
                        aR[m * 2 + kk], bR[n * 2 + kk], acc[m][n], 0, 0, 0);
        __builtin_amdgcn_s_setprio(0);

        // ---- phase C: a(m=4..7) reads; fence reads; barrier; prefetch t+2; MFMA rest ----
        #pragma unroll
        for (int m = 0; m < 4; ++m) {
            a2[m * 2 + 0] = *(const bf16x8*)(ra + (m + 4) * 1024 + col0);
            a2[m * 2 + 1] = *(const bf16x8*)(ra + (m + 4) * 1024 + col1);
        }
        asm volatile("s_waitcnt lgkmcnt(0)" ::: "memory");   // my reads of buf[cur] done
        __builtin_amdgcn_sched_barrier(0);
        __builtin_amdgcn_s_barrier();                        // all waves done reading buf[cur]
        __builtin_amdgcn_sched_barrier(0);
        if (t + 2 < NT) STAGE(cur, (t + 2) * BK2);           // overwrite buf[cur] with tile t+2

        __builtin_amdgcn_s_setprio(1);
        #pragma unroll
        for (int kk = 0; kk < 2; ++kk)                       // kk OUTER: 16 indep MFMA per kk
            #pragma unroll
            for (int m = 0; m < 4; ++m)
                #pragma unroll
                for (int n = 0; n < 4; ++n)
                    acc[m + 4][n] = __builtin_amdgcn_mfma_f32_16x16x32_bf16(
                        a2[m * 2 + kk], bR[n * 2 + kk], acc[m + 4][n], 0, 0, 0);
        __builtin_amdgcn_s_setprio(0);

        // tile t+1 (8 oldest outstanding loads) must be complete before next iter
        if (t + 2 < NT) { asm volatile("s_waitcnt vmcnt(8)" ::: "memory"); }
        else            { asm volatile("s_waitcnt vmcnt(0)" ::: "memory"); }
        __builtin_amdgcn_sched_barrier(0);
        __builtin_amdgcn_s_barrier();
        __builtin_amdgcn_sched_barrier(0);
    }

    // ---- epilogue: C/D layout col=lane&15, row=(lane>>4)*4+r ----
    const int cn  = lane & 15;
    const int cr4 = (lane >> 4) * 4;
    #pragma unroll
    for (int n = 0; n < 4; ++n) {
        const int col = n0 + wn + n * 16 + cn;
        const float bv = bias[col];
        #pragma unroll
        for (int m = 0; m < 8; ++m) {
            const int row = m0 + wm + m * 16 + cr4;
            #pragma unroll
            for (int r = 0; r < 4; ++r)
                out[(size_t)(row + r) * N_DIM + col] = acc[m][n][r] + bv;
        }
    }
}

// ================= fallback: fused kernel (if ws too small) =================
#define FBM 128
#define FBN 128
#define FBK 32
#define FLDSS 40
__global__ __launch_bounds__(256) void gptq_gemm_fused_kernel(
    const float* __restrict__ x, const int* __restrict__ qw, const int* __restrict__ qz,
    const float* __restrict__ sc, const float* __restrict__ bias, float* __restrict__ out)
{
    __shared__ __align__(16) __bf16 Asm[FBM][FLDSS];
    __shared__ __align__(16) __bf16 Bsm[FBN][FLDSS];
    const int tid = threadIdx.x, lane = tid & 63, wid = tid >> 6;
    const int m0 = blockIdx.y * FBM, n0 = blockIdx.x * FBN;
    const int wm = (wid >> 1) * 64, wn = (wid & 1) * 64;
    f32x4 acc[4][4];
    #pragma unroll
    for (int i = 0; i < 4; ++i)
        #pragma unroll
        for (int j = 0; j < 4; ++j) acc[i][j] = (f32x4){0.f, 0.f, 0.f, 0.f};
    const int a_m = tid >> 2, a_h = tid & 3;
    const int b_n = tid & 127, b_k8 = tid >> 7;
    const int ng = n0 + b_n, zsh = (ng & 7) * 4;
    const int fr = lane & 15, fc = lane >> 4;
    for (int k0 = 0; k0 < K_DIM; k0 += FBK) {
        const int g = k0 >> 7;
        const float* xa = x + (size_t)(m0 + a_m) * K_DIM + k0 + a_h * 8;
        f32x4 a0 = *(const f32x4*)xa;
        f32x4 a1 = *(const f32x4*)(xa + 4);
        const float* xbp = xa + (size_t)64 * K_DIM;
        f32x4 a2 = *(const f32x4*)xbp;
        f32x4 a3 = *(const f32x4*)(xbp + 4);
        const int kb = (k0 >> 3) + b_k8;
        const int w0 = qw[(size_t)kb * N_DIM + ng];
        const int w1 = qw[(size_t)(kb + 2) * N_DIM + ng];
        const float s = sc[(size_t)g * N_DIM + ng];
        const float nzs = -(float)((qz[(size_t)g * (N_DIM / 8) + (ng >> 3)] >> zsh) & 15) * s;
        __syncthreads();
        bf16x8 av0, av1;
        #pragma unroll
        for (int j = 0; j < 4; ++j) {
            av0[j] = f2bf(a0[j]); av0[j + 4] = f2bf(a1[j]);
            av1[j] = f2bf(a2[j]); av1[j + 4] = f2bf(a3[j]);
        }
        *(bf16x8*)&Asm[a_m][a_h * 8] = av0;
        *(bf16x8*)&Asm[a_m + 64][a_h * 8] = av1;
        bf16x8 bv0, bv1;
        #pragma unroll
        for (int j = 0; j < 8; ++j) {
            bv0[j] = f2bf(fmaf((float)((w0 >> (4 * j)) & 15), s, nzs));
            bv1[j] = f2bf(fmaf((float)((w1 >> (4 * j)) & 15), s, nzs));
        }
        *(bf16x8*)&Bsm[b_n][b_k8 * 8] = bv0;
        *(bf16x8*)&Bsm[b_n][(b_k8 + 2) * 8] = bv1;
        __syncthreads();
        bf16x8 af[4], bfr[4];
        #pragma unroll
        for (int i = 0; i < 4; ++i) af[i] = *(const bf16x8*)&Asm[wm + i * 16 + fr][fc * 8];
        #pragma unroll
        for (int j = 0; j < 4; ++j) bfr[j] = *(const bf16x8*)&Bsm[wn + j * 16 + fr][fc * 8];
        #pragma unroll
        for (int i = 0; i < 4; ++i)
            #pragma unroll
            for (int j = 0; j < 4; ++j)
                acc[i][j] = __builtin_amdgcn_mfma_f32_16x16x32_bf16(af[i], bfr[j], acc[i][j], 0, 0, 0);
    }
    const int cn = lane & 15, cr4 = (lane >> 4) * 4;
    #pragma unroll
    for (int j = 0; j < 4; ++j) {
        const int col = n0 + wn + j * 16 + cn;
        const float bv = bias[col];
        #pragma unroll
        for (int i = 0; i < 4; ++i) {
            const int row = m0 + wm + i * 16 + cr4;
            #pragma unroll
            for (int r = 0; r < 4; ++r)
                out[(size_t)(row + r) * N_DIM + col] = acc[i][j][r] + bv;
        }
    }
}

extern "C" void kernel_launch(void* const* d_in, const int* in_sizes, int n_in,
                              void* d_out, int out_size, void* d_ws, size_t ws_size,
                              hipStream_t stream) {
    const float* x    = (const float*)d_in[0];
    const int*   qw   = (const int*)d_in[1];
    const int*   qz   = (const int*)d_in[2];
    const float* sc   = (const float*)d_in[3];
    const float* bias = (const float*)d_in[4];
    float* out = (float*)d_out;
    const int M = in_sizes[0] / K_DIM;   // 4096

    const size_t xb_bytes = (size_t)M * K_DIM * sizeof(__bf16);        // 32 MiB
    const size_t wb_bytes = (size_t)N_DIM * K_DIM * sizeof(__bf16);    // 86 MiB
    if (ws_size >= xb_bytes + wb_bytes && (M % BM2) == 0) {
        __bf16* xb = (__bf16*)d_ws;
        __bf16* wb = (__bf16*)((uint8_t*)d_ws + xb_bytes);
        const int total8 = M * K_DIM / 8;
        cvt_x_kernel<<<dim3(total8 / 256), dim3(256), 0, stream>>>(x, xb, total8);
        dequant_w_kernel<<<dim3(N_DIM / 256, K_DIM / 8 / 8), dim3(256), 0, stream>>>(qw, qz, sc, wb);
        const int nblocks = (N_DIM / BN2) * (M / BM2);   // 43 * 16 = 688
        gemm256_kernel<<<dim3(nblocks), dim3(512), 0, stream>>>(xb, wb, bias, out);
    } else {
        gptq_gemm_fused_kernel<<<dim3(N_DIM / FBN, M / FBM), dim3(256), 0, stream>>>(x, qw, qz, sc, bias, out);
    }
}